// Round 3
// baseline (979.038 us; speedup 1.0000x reference)
//
#include <hip/hip_runtime.h>

// Problem constants (fixed by the reference)
#define Bn 2
#define Nn 256
#define Mn 512
#define Cn 256
#define Hn 8
#define MT 128            // m-tile size in fused kernel
#define ROWS 2            // n-rows per block in fused kernel
#define SCALE_ 0.17677669529663687f   // Dh^-0.5, Dh=32

typedef short bf16x8 __attribute__((ext_vector_type(8)));
typedef float f32x4 __attribute__((ext_vector_type(4)));

static __device__ __forceinline__ short f2b(float f) {   // RNE f32->bf16
    unsigned u = __builtin_bit_cast(unsigned, f);
    u += 0x7fffu + ((u >> 16) & 1u);
    return (short)(u >> 16);
}

// ---- convert W1/W2 (f32 -> bf16), 65536 elems each ----
__global__ void convert_w(const float* __restrict__ W1, const float* __restrict__ W2,
                          short* __restrict__ W1b, short* __restrict__ W2b) {
    int i = blockIdx.x * 256 + threadIdx.x;
    W1b[i] = f2b(W1[i]);
    W2b[i] = f2b(W2[i]);
}

// ---- row-linear: out[r][c] = sum_k A[r][k]*W[c][k] (+bias) (+res), 32 rows/block ----
__global__ __launch_bounds__(256) void linear32(
        const float* __restrict__ A, const float* __restrict__ W,
        const float* __restrict__ bias, const float* __restrict__ res,
        float* __restrict__ out) {
    __shared__ float arow[32][Cn];
    const int r0 = blockIdx.x * 32;
    const int t = threadIdx.x;
    #pragma unroll
    for (int i = 0; i < 32; ++i) arow[i][t] = A[(size_t)(r0 + i) * Cn + t];
    __syncthreads();
    float acc[32];
    #pragma unroll
    for (int i = 0; i < 32; ++i) acc[i] = 0.f;
    const float* wr = W + (size_t)t * Cn;
    for (int k = 0; k < Cn; k += 4) {
        const float4 wv = *(const float4*)(wr + k);
        #pragma unroll
        for (int i = 0; i < 32; ++i)
            acc[i] += arow[i][k] * wv.x + arow[i][k+1] * wv.y
                    + arow[i][k+2] * wv.z + arow[i][k+3] * wv.w;
    }
    const float bv = bias ? bias[t] : 0.0f;
    #pragma unroll
    for (int i = 0; i < 32; ++i) {
        float o = acc[i] + bv;
        if (res) o += res[(size_t)(r0 + i) * Cn + t];
        out[(size_t)(r0 + i) * Cn + t] = o;
    }
}

// ---- fused attention: W1/W2 register-resident, per-head wave-local softmax ----
// 512 threads = 8 waves; wave w owns output-channel slice [w*32, w*32+32) == head w.
__global__ __launch_bounds__(512, 2) void fused_attn(
        const float* __restrict__ qp, const float* __restrict__ kp,
        const float* __restrict__ vp, const float* __restrict__ qpos,
        const short* __restrict__ W1b, const short* __restrict__ W2b,
        const float* __restrict__ b1, const float* __restrict__ b2,
        const float* __restrict__ freqs, float* __restrict__ xout) {
    __shared__ __align__(16) char embS[MT * 512];   // 128 x 256 bf16, XOR-swizzled (emb, then S)
    __shared__ float scb2[Hn * MT];                 // [h][m] scores -> weights
    __shared__ float pacc[512];
    __shared__ float mxL[Hn], lL[Hn], corrL[Hn];

    const int t = threadIdx.x;
    const int lane = t & 63;
    const int w = t >> 6;                 // wave id = head id = col-slice id
    const int lr = lane & 15, lg = lane >> 4;

    // XCD-chunked bijective swizzle: 256 blocks = 8 XCDs x 32 contiguous
    const int blk = ((blockIdx.x & 7) << 5) | (blockIdx.x >> 3);
    const int qrow0 = blk * ROWS;
    const int b = qrow0 >> 8;             // batch (ROWS divides Nn)

    // --- W1/W2 register-resident B-fragments for cols c = w*32 + jb*16 + lr ---
    bf16x8 w1r[16], w2r[16];
    {
        #pragma unroll
        for (int jb = 0; jb < 2; ++jb) {
            const short* p1 = W1b + (size_t)(w * 32 + jb * 16 + lr) * Cn + lg * 8;
            const short* p2 = W2b + (size_t)(w * 32 + jb * 16 + lr) * Cn + lg * 8;
            #pragma unroll
            for (int kk = 0; kk < 8; ++kk) {
                w1r[jb * 8 + kk] = *(const bf16x8*)(p1 + kk * 32);
                w2r[jb * 8 + kk] = *(const bf16x8*)(p2 + kk * 32);
            }
        }
    }
    const int cA = w * 32 + lr, cB = cA + 16;
    const float b1v0 = b1[cA], b1v1 = b1[cB];
    const float b2v0 = b2[cA], b2v1 = b2[cB];
    const float fv = freqs[t & 127];
    const f32x4 vzero = {0.f, 0.f, 0.f, 0.f};

    for (int rn = 0; rn < ROWS; ++rn) {
        const int qrow = qrow0 + rn;
        const float q0 = qp[(size_t)qrow * Cn + cA];
        const float q1 = qp[(size_t)qrow * Cn + cB];
        if (t < Hn) { mxL[t] = -1e30f; lL[t] = 0.f; corrL[t] = 1.f; }
        float xacc = 0.f;
        __syncthreads();

        for (int m0 = 0; m0 < Mn; m0 += MT) {
            // phase 1: embeddings -> embS. thread: f = t&127, rows m = it*4 + (t>>7)
            {
                const int f = t & 127, mb = t >> 7;
                #pragma unroll 4
                for (int it = 0; it < 32; ++it) {
                    const int m = it * 4 + mb;
                    const float tv = qpos[(size_t)qrow * Mn + m0 + m];
                    float sv, cv;
                    __sincosf(tv * fv, &sv, &cv);
                    const int base = m * 512, sw = (m & 7) << 4;
                    *(short*)(embS + ((base + f * 2) ^ sw)) = f2b(cv);        // cos -> [0:128)
                    *(short*)(embS + ((base + 256 + f * 2) ^ sw)) = f2b(sv);  // sin -> [128:256)
                }
            }
            __syncthreads();

            // phase 2: GEMM1  hidden = emb @ W1^T  (acc in regs, B from regs)
            f32x4 acc[8][2];
            #pragma unroll
            for (int pb = 0; pb < 8; ++pb) { acc[pb][0] = vzero; acc[pb][1] = vzero; }
            #pragma unroll
            for (int pb = 0; pb < 8; ++pb) {
                const int row = pb * 16 + lr;
                const int sw = (row & 7) << 4;
                const int rb = row * 512 + lg * 16;
                #pragma unroll
                for (int kk = 0; kk < 8; ++kk) {
                    const bf16x8 a = *(const bf16x8*)(embS + ((rb + kk * 64) ^ sw));
                    acc[pb][0] = __builtin_amdgcn_mfma_f32_16x16x32_bf16(a, w1r[kk],     acc[pb][0], 0, 0, 0);
                    acc[pb][1] = __builtin_amdgcn_mfma_f32_16x16x32_bf16(a, w1r[8 + kk], acc[pb][1], 0, 0, 0);
                }
            }
            __syncthreads();                   // all emb reads done

            // store S = silu(hidden + b1) back into embS
            #pragma unroll
            for (int pb = 0; pb < 8; ++pb) {
                #pragma unroll
                for (int jb = 0; jb < 2; ++jb) {
                    const float bv = jb ? b1v1 : b1v0;
                    const int j = w * 32 + jb * 16 + lr;
                    #pragma unroll
                    for (int r = 0; r < 4; ++r) {
                        const int row = pb * 16 + lg * 4 + r;   // C/D: row = 4*(lane>>4)+reg
                        float hv = acc[pb][jb][r] + bv;
                        hv = hv / (1.f + __expf(-hv));
                        *(short*)(embS + (((row * 512 + j * 2)) ^ ((row & 7) << 4))) = f2b(hv);
                    }
                }
            }
            __syncthreads();

            // phase 3: GEMM2  P = S @ W2^T   (P stays in acc registers!)
            #pragma unroll
            for (int pb = 0; pb < 8; ++pb) { acc[pb][0] = vzero; acc[pb][1] = vzero; }
            #pragma unroll
            for (int pb = 0; pb < 8; ++pb) {
                const int row = pb * 16 + lr;
                const int sw = (row & 7) << 4;
                const int rb = row * 512 + lg * 16;
                #pragma unroll
                for (int kk = 0; kk < 8; ++kk) {
                    const bf16x8 a = *(const bf16x8*)(embS + ((rb + kk * 64) ^ sw));
                    acc[pb][0] = __builtin_amdgcn_mfma_f32_16x16x32_bf16(a, w2r[kk],     acc[pb][0], 0, 0, 0);
                    acc[pb][1] = __builtin_amdgcn_mfma_f32_16x16x32_bf16(a, w2r[8 + kk], acc[pb][1], 0, 0, 0);
                }
            }

            // phase 4: scores for head w straight from registers.
            // lane (lr,lg) holds P[m = pb*16+lg*4+r][c = w*32 + jb*16 + lr]
            #pragma unroll
            for (int pb = 0; pb < 8; ++pb) {
                #pragma unroll
                for (int r = 0; r < 4; ++r) {
                    const int m = pb * 16 + lg * 4 + r;
                    const float* krow = kp + ((size_t)(b * Mn + m0 + m)) * Cn;
                    float v = (acc[pb][0][r] + b2v0) * q0 * krow[cA]
                            + (acc[pb][1][r] + b2v1) * q1 * krow[cB];
                    v += __shfl_xor(v, 1);
                    v += __shfl_xor(v, 2);
                    v += __shfl_xor(v, 4);
                    v += __shfl_xor(v, 8);
                    if (lr == 0) scb2[w * MT + m] = v * SCALE_;
                }
            }

            // phase 5: wave-local online softmax for head w
            {
                float s0 = scb2[w * MT + lane];
                float s1 = scb2[w * MT + 64 + lane];
                float tmax = fmaxf(s0, s1);
                #pragma unroll
                for (int msk = 1; msk < 64; msk <<= 1) tmax = fmaxf(tmax, __shfl_xor(tmax, msk));
                const float mold = mxL[w];
                const float mnew = fmaxf(mold, tmax);
                const float corr = __expf(mold - mnew);
                const float e0 = __expf(s0 - mnew);
                const float e1 = __expf(s1 - mnew);
                scb2[w * MT + lane] = e0;
                scb2[w * MT + 64 + lane] = e1;
                float ss = e0 + e1;
                #pragma unroll
                for (int msk = 1; msk < 64; msk <<= 1) ss += __shfl_xor(ss, msk);
                if (lane == 0) { lL[w] = lL[w] * corr + ss; mxL[w] = mnew; corrL[w] = corr; }
            }
            __syncthreads();

            // phase 6: PV partial sums (t<256: m-half 0, t>=256: m-half 1)
            {
                const int e = t & 255, half = t >> 8;
                const int oh = e >> 5, od = e & 31;
                const float* vr = vp + ((size_t)(b * Mn + m0 + half * 64)) * Cn + oh * 32 + od;
                const float* wr = scb2 + oh * MT + half * 64;
                float s = 0.f;
                #pragma unroll 4
                for (int m = 0; m < 64; ++m) s += wr[m] * vr[(size_t)m * Cn];
                pacc[t] = s;
            }
            __syncthreads();
            if (t < 256) xacc = xacc * corrL[t >> 5] + pacc[t] + pacc[t + 256];
            __syncthreads();   // protect scb2/pacc/corrL before next tile
        }
        if (t < 256) xout[(size_t)qrow * Cn + t] = xacc / lL[t >> 5];
        __syncthreads();       // protect mxL/lL before next row's reset
    }
}

extern "C" void kernel_launch(void* const* d_in, const int* in_sizes, int n_in,
                              void* d_out, int out_size, void* d_ws, size_t ws_size,
                              hipStream_t stream) {
    const float* query = (const float*)d_in[0];
    const float* key   = (const float*)d_in[1];
    const float* qpos  = (const float*)d_in[2];
    const float* Wq    = (const float*)d_in[3];
    const float* bq    = (const float*)d_in[4];
    const float* Wk    = (const float*)d_in[5];
    const float* Wv    = (const float*)d_in[6];
    const float* bv    = (const float*)d_in[7];
    const float* Wo    = (const float*)d_in[8];
    const float* bo    = (const float*)d_in[9];
    const float* W1    = (const float*)d_in[10];
    const float* b1    = (const float*)d_in[11];
    const float* W2    = (const float*)d_in[12];
    const float* b2    = (const float*)d_in[13];
    const float* freqs = (const float*)d_in[14];
    float* out = (float*)d_out;

    char* ws = (char*)d_ws;
    float* qp  = (float*)(ws);                 // 512 KB  (B*N*C f32)
    float* kp  = (float*)(ws + 524288);        // 1 MB    (B*M*C f32)
    float* vp  = (float*)(ws + 1572864);       // 1 MB
    float* xo  = (float*)(ws + 2621440);       // 512 KB
    short* W1b = (short*)(ws + 3145728);       // 128 KB bf16
    short* W2b = (short*)(ws + 3276800);       // 128 KB bf16

    convert_w<<<256, 256, 0, stream>>>(W1, W2, W1b, W2b);
    linear32<<<16, 256, 0, stream>>>(query, Wq, bq, nullptr, qp);     // q'
    linear32<<<32, 256, 0, stream>>>(key, Wk, nullptr, nullptr, kp);  // k' (no bias)
    linear32<<<32, 256, 0, stream>>>(key, Wv, bv, nullptr, vp);       // v'
    fused_attn<<<(Bn * Nn) / ROWS, 512, 0, stream>>>(qp, kp, vp, qpos, W1b, W2b, b1, b2, freqs, xo);
    linear32<<<16, 256, 0, stream>>>(xo, Wo, bo, query, out);         // out = x@Wo^T+bo+query
}

// Round 4
// 545.034 us; speedup vs baseline: 1.7963x; 1.7963x over previous
//
#include <hip/hip_runtime.h>

// Problem constants (fixed by the reference)
#define Bn 2
#define Nn 256
#define Mn 512
#define Cn 256
#define Hn 8
#define MT 64             // m-tile size in fused kernel
#define SCALE_ 0.17677669529663687f   // Dh^-0.5, Dh=32

typedef short bf16x8 __attribute__((ext_vector_type(8)));
typedef float f32x4 __attribute__((ext_vector_type(4)));

static __device__ __forceinline__ float b2f(short s) {
    unsigned u = ((unsigned)(unsigned short)s) << 16;
    return __builtin_bit_cast(float, u);
}
static __device__ __forceinline__ short f2b(float f) {   // RNE f32->bf16
    unsigned u = __builtin_bit_cast(unsigned, f);
    u += 0x7fffu + ((u >> 16) & 1u);
    return (short)(u >> 16);
}

// ---- convert W1/W2 (f32 -> bf16), 65536 elems each ----
__global__ void convert_w(const float* __restrict__ W1, const float* __restrict__ W2,
                          short* __restrict__ W1b, short* __restrict__ W2b) {
    int i = blockIdx.x * 256 + threadIdx.x;
    W1b[i] = f2b(W1[i]);
    W2b[i] = f2b(W2[i]);
}

// ---- row-linear: out[r][c] = sum_k A[r][k]*W[c][k] (+bias) (+res), 32 rows/block ----
template <bool BF16OUT>
__global__ __launch_bounds__(256) void linear32(
        const float* __restrict__ A, const float* __restrict__ W,
        const float* __restrict__ bias, const float* __restrict__ res,
        float* __restrict__ outf, short* __restrict__ outb) {
    __shared__ float arow[32][Cn];
    const int r0 = blockIdx.x * 32;
    const int t = threadIdx.x;
    #pragma unroll
    for (int i = 0; i < 32; ++i) arow[i][t] = A[(size_t)(r0 + i) * Cn + t];
    __syncthreads();
    float acc[32];
    #pragma unroll
    for (int i = 0; i < 32; ++i) acc[i] = 0.f;
    const float* wr = W + (size_t)t * Cn;
    for (int k = 0; k < Cn; k += 4) {
        const float4 wv = *(const float4*)(wr + k);
        #pragma unroll
        for (int i = 0; i < 32; ++i)
            acc[i] += arow[i][k] * wv.x + arow[i][k+1] * wv.y
                    + arow[i][k+2] * wv.z + arow[i][k+3] * wv.w;
    }
    const float bv = bias ? bias[t] : 0.0f;
    #pragma unroll
    for (int i = 0; i < 32; ++i) {
        float o = acc[i] + bv;
        if (res) o += res[(size_t)(r0 + i) * Cn + t];
        if (BF16OUT) outb[(size_t)(r0 + i) * Cn + t] = f2b(o);
        else         outf[(size_t)(r0 + i) * Cn + t] = o;
    }
}

// ---- fused attention: W1/W2 register-resident, k/v LDS-staged bf16, 1 qrow/block ----
// 512 threads = 8 waves; wave w owns output-channel slice [w*32, w*32+32) == head w.
__global__ __launch_bounds__(512) void fused_attn(
        const float* __restrict__ qp, const short* __restrict__ kpb,
        const short* __restrict__ vpb, const float* __restrict__ qpos,
        const short* __restrict__ W1b, const short* __restrict__ W2b,
        const float* __restrict__ b1, const float* __restrict__ b2,
        const float* __restrict__ freqs, float* __restrict__ xout) {
    __shared__ __align__(16) char embS[MT * 512];   // 32 KB: emb/S (XOR-swizzled), then V (plain)
    __shared__ __align__(16) char kS[MT * 512];     // 32 KB: K tile bf16, plain [m][c]
    __shared__ float scb2[Hn * MT];                 // scores -> weights
    __shared__ float pacc[512];
    __shared__ float corrS[Hn], lS[Hn];

    const int t = threadIdx.x;
    const int lane = t & 63;
    const int w = t >> 6;                 // wave id = head id = col-slice id
    const int lr = lane & 15, lg = lane >> 4;

    // XCD-chunked bijective swizzle: 512 blocks = 8 XCDs x 64 contiguous
    const int qrow = ((blockIdx.x & 7) << 6) | (blockIdx.x >> 3);
    const int b = qrow >> 8;              // batch

    // --- W1/W2 register-resident B-fragments for cols c = w*32 + jb*16 + lr ---
    bf16x8 w1r[16], w2r[16];
    #pragma unroll
    for (int jb = 0; jb < 2; ++jb) {
        const short* p1 = W1b + (size_t)(w * 32 + jb * 16 + lr) * Cn + lg * 8;
        const short* p2 = W2b + (size_t)(w * 32 + jb * 16 + lr) * Cn + lg * 8;
        #pragma unroll
        for (int kk = 0; kk < 8; ++kk) {
            w1r[jb * 8 + kk] = *(const bf16x8*)(p1 + kk * 32);
            w2r[jb * 8 + kk] = *(const bf16x8*)(p2 + kk * 32);
        }
    }
    const int cA = w * 32 + lr, cB = cA + 16;
    const float b1v0 = b1[cA], b1v1 = b1[cB];
    const float b2v0 = b2[cA], b2v1 = b2[cB];
    const float q0 = qp[(size_t)qrow * Cn + cA];
    const float q1 = qp[(size_t)qrow * Cn + cB];
    const float fv = freqs[t & 127];
    float m_run = -1e30f, l_run = 0.f;
    float xacc = 0.f;                     // meaningful for t<256 (output channel t)
    const f32x4 vzero = {0.f, 0.f, 0.f, 0.f};

    for (int m0 = 0; m0 < Mn; m0 += MT) {
        const size_t tbase = ((size_t)(b * Mn + m0)) * 512;   // tile byte offset in kpb/vpb

        // issue K-tile loads early (latency hides under sincos)
        float4 kreg[4];
        #pragma unroll
        for (int i = 0; i < 4; ++i)
            kreg[i] = *(const float4*)((const char*)kpb + tbase + i * 8192 + t * 16);

        // phase 1: embeddings -> embS (swizzled). thread: f = t&127, rows m = it*4 + (t>>7)
        {
            const int f = t & 127, mb = t >> 7;
            #pragma unroll 2
            for (int it = 0; it < 16; ++it) {
                const int m = it * 4 + mb;
                const float tv = qpos[(size_t)qrow * Mn + m0 + m];
                float sv, cv;
                __sincosf(tv * fv, &sv, &cv);
                char* rowp = embS + m * 512;
                const int sw = (m & 7) << 4;
                *(short*)(rowp + ((f * 2) ^ sw)) = f2b(cv);         // cos -> [0:128)
                *(short*)(rowp + ((256 + f * 2) ^ sw)) = f2b(sv);   // sin -> [128:256)
            }
        }
        // K regs -> kS (plain, conflict-free: lane-consecutive 16B)
        #pragma unroll
        for (int i = 0; i < 4; ++i)
            *(float4*)(kS + i * 8192 + t * 16) = kreg[i];
        __syncthreads();

        // issue V-tile loads (consumed after GEMM2)
        float4 vreg[4];
        #pragma unroll
        for (int i = 0; i < 4; ++i)
            vreg[i] = *(const float4*)((const char*)vpb + tbase + i * 8192 + t * 16);

        // phase 2: GEMM1  hidden = emb @ W1^T
        f32x4 acc[4][2];
        #pragma unroll
        for (int pb = 0; pb < 4; ++pb) { acc[pb][0] = vzero; acc[pb][1] = vzero; }
        #pragma unroll
        for (int pb = 0; pb < 4; ++pb) {
            const int row = pb * 16 + lr;
            const int sw = (row & 7) << 4;
            const char* rowp = embS + row * 512;
            #pragma unroll
            for (int kk = 0; kk < 8; ++kk) {
                const bf16x8 a = *(const bf16x8*)(rowp + ((lg * 16 + kk * 64) ^ sw));
                acc[pb][0] = __builtin_amdgcn_mfma_f32_16x16x32_bf16(a, w1r[kk],     acc[pb][0], 0, 0, 0);
                acc[pb][1] = __builtin_amdgcn_mfma_f32_16x16x32_bf16(a, w1r[8 + kk], acc[pb][1], 0, 0, 0);
            }
        }
        __syncthreads();                   // all emb reads done

        // store S = silu(hidden + b1) back into embS (swizzled)
        #pragma unroll
        for (int pb = 0; pb < 4; ++pb) {
            #pragma unroll
            for (int jb = 0; jb < 2; ++jb) {
                const float bv = jb ? b1v1 : b1v0;
                const int j = w * 32 + jb * 16 + lr;
                #pragma unroll
                for (int r = 0; r < 4; ++r) {
                    const int row = pb * 16 + lg * 4 + r;   // C/D: row = 4*(lane>>4)+reg
                    float hv = acc[pb][jb][r] + bv;
                    hv = hv / (1.f + __expf(-hv));
                    *(short*)(embS + row * 512 + ((j * 2) ^ ((row & 7) << 4))) = f2b(hv);
                }
            }
        }
        __syncthreads();

        // phase 3: GEMM2  P = S @ W2^T  (P stays in registers)
        #pragma unroll
        for (int pb = 0; pb < 4; ++pb) { acc[pb][0] = vzero; acc[pb][1] = vzero; }
        #pragma unroll
        for (int pb = 0; pb < 4; ++pb) {
            const int row = pb * 16 + lr;
            const int sw = (row & 7) << 4;
            const char* rowp = embS + row * 512;
            #pragma unroll
            for (int kk = 0; kk < 8; ++kk) {
                const bf16x8 a = *(const bf16x8*)(rowp + ((lg * 16 + kk * 64) ^ sw));
                acc[pb][0] = __builtin_amdgcn_mfma_f32_16x16x32_bf16(a, w2r[kk],     acc[pb][0], 0, 0, 0);
                acc[pb][1] = __builtin_amdgcn_mfma_f32_16x16x32_bf16(a, w2r[8 + kk], acc[pb][1], 0, 0, 0);
            }
        }
        __syncthreads();                   // all S reads done; embS free

        // V regs -> embS (plain layout [m][c])
        #pragma unroll
        for (int i = 0; i < 4; ++i)
            *(float4*)(embS + i * 8192 + t * 16) = vreg[i];

        // phase 4: scores for head w from P-registers + kS
        #pragma unroll
        for (int pb = 0; pb < 4; ++pb) {
            #pragma unroll
            for (int r = 0; r < 4; ++r) {
                const int m = pb * 16 + lg * 4 + r;
                const float k0 = b2f(*(const short*)(kS + m * 512 + cA * 2));
                const float k1 = b2f(*(const short*)(kS + m * 512 + cB * 2));
                float v = (acc[pb][0][r] + b2v0) * q0 * k0
                        + (acc[pb][1][r] + b2v1) * q1 * k1;
                v += __shfl_xor(v, 1);
                v += __shfl_xor(v, 2);
                v += __shfl_xor(v, 4);
                v += __shfl_xor(v, 8);
                if (lr == 0) scb2[w * MT + m] = v * SCALE_;
            }
        }

        // phase 5: wave-local online softmax for head w (running m/l in registers)
        {
            const float s = scb2[w * MT + lane];
            float tmax = s;
            #pragma unroll
            for (int msk = 1; msk < 64; msk <<= 1) tmax = fmaxf(tmax, __shfl_xor(tmax, msk));
            const float mnew = fmaxf(m_run, tmax);
            const float corr = __expf(m_run - mnew);
            const float e = __expf(s - mnew);
            scb2[w * MT + lane] = e;
            float ss = e;
            #pragma unroll
            for (int msk = 1; msk < 64; msk <<= 1) ss += __shfl_xor(ss, msk);
            l_run = l_run * corr + ss;
            m_run = mnew;
            if (lane == 0) corrS[w] = corr;
        }
        __syncthreads();                   // weights + V-in-embS + corrS visible to all

        // phase 6: PV partial sums. thread: c = t&255, m-half = t>>8
        {
            const int c = t & 255, half = t >> 8;
            const int h = c >> 5;
            const char* vb = embS + (half * 32) * 512 + c * 2;
            const float* wr2 = scb2 + h * MT + half * 32;
            float s = 0.f;
            #pragma unroll 8
            for (int m = 0; m < 32; ++m)
                s += wr2[m] * b2f(*(const short*)(vb + m * 512));
            pacc[t] = s;
        }
        __syncthreads();
        if (t < 256) xacc = xacc * corrS[t >> 5] + pacc[t] + pacc[t + 256];
        __syncthreads();                   // pacc/scb2/embS free for next tile
    }

    if (lane == 0) lS[w] = l_run;
    __syncthreads();
    if (t < 256) xout[(size_t)qrow * Cn + t] = xacc / lS[t >> 5];
}

extern "C" void kernel_launch(void* const* d_in, const int* in_sizes, int n_in,
                              void* d_out, int out_size, void* d_ws, size_t ws_size,
                              hipStream_t stream) {
    const float* query = (const float*)d_in[0];
    const float* key   = (const float*)d_in[1];
    const float* qpos  = (const float*)d_in[2];
    const float* Wq    = (const float*)d_in[3];
    const float* bq    = (const float*)d_in[4];
    const float* Wk    = (const float*)d_in[5];
    const float* Wv    = (const float*)d_in[6];
    const float* bv    = (const float*)d_in[7];
    const float* Wo    = (const float*)d_in[8];
    const float* bo    = (const float*)d_in[9];
    const float* W1    = (const float*)d_in[10];
    const float* b1    = (const float*)d_in[11];
    const float* W2    = (const float*)d_in[12];
    const float* b2    = (const float*)d_in[13];
    const float* freqs = (const float*)d_in[14];
    float* out = (float*)d_out;

    char* ws = (char*)d_ws;
    float* qp  = (float*)(ws);                 // 512 KB  (B*N*C f32)
    short* kpb = (short*)(ws + 524288);        // 512 KB  (B*M*C bf16)
    short* vpb = (short*)(ws + 1048576);       // 512 KB
    float* xo  = (float*)(ws + 1572864);       // 512 KB
    short* W1b = (short*)(ws + 2097152);       // 128 KB bf16
    short* W2b = (short*)(ws + 2228224);       // 128 KB bf16

    convert_w<<<256, 256, 0, stream>>>(W1, W2, W1b, W2b);
    linear32<false><<<16, 256, 0, stream>>>(query, Wq, bq, nullptr, qp, nullptr);   // q' f32
    linear32<true ><<<32, 256, 0, stream>>>(key, Wk, nullptr, nullptr, nullptr, kpb); // k' bf16
    linear32<true ><<<32, 256, 0, stream>>>(key, Wv, bv, nullptr, nullptr, vpb);      // v' bf16
    fused_attn<<<Bn * Nn, 512, 0, stream>>>(qp, kpb, vpb, qpos, W1b, W2b, b1, b2, freqs, xo);
    linear32<false><<<16, 256, 0, stream>>>(xo, Wo, bo, query, out, nullptr);       // out
}

// Round 5
// 316.361 us; speedup vs baseline: 3.0947x; 1.7228x over previous
//
#include <hip/hip_runtime.h>

// Problem constants (fixed by the reference)
#define Bn 2
#define Nn 256
#define Mn 512
#define Cn 256
#define Hn 8
#define MT 64             // m-tile size in fused kernel
#define SCALE_ 0.17677669529663687f   // Dh^-0.5, Dh=32

typedef short bf16x8 __attribute__((ext_vector_type(8)));
typedef float f32x4 __attribute__((ext_vector_type(4)));

static __device__ __forceinline__ float b2f(short s) {
    unsigned u = ((unsigned)(unsigned short)s) << 16;
    return __builtin_bit_cast(float, u);
}
static __device__ __forceinline__ short f2b(float f) {   // RNE f32->bf16
    unsigned u = __builtin_bit_cast(unsigned, f);
    u += 0x7fffu + ((u >> 16) & 1u);
    return (short)(u >> 16);
}
static __device__ __forceinline__ void async16(const void* g, void* l) {
    __builtin_amdgcn_global_load_lds(
        (const __attribute__((address_space(1))) unsigned int*)g,
        (__attribute__((address_space(3))) unsigned int*)l, 16, 0, 0);
}

// ---- convert W1/W2 (f32 -> bf16), 65536 elems each ----
__global__ void convert_w(const float* __restrict__ W1, const float* __restrict__ W2,
                          short* __restrict__ W1b, short* __restrict__ W2b) {
    int i = blockIdx.x * 256 + threadIdx.x;
    W1b[i] = f2b(W1[i]);
    W2b[i] = f2b(W2[i]);
}

// ---- row-linear, column-split: block = 32 rows x 64 cols ----
template <bool BF16OUT>
__global__ __launch_bounds__(256) void linear_rc(
        const float* __restrict__ A, const float* __restrict__ W,
        const float* __restrict__ bias, const float* __restrict__ res,
        float* __restrict__ outf, short* __restrict__ outb) {
    __shared__ float arow[32][Cn];
    const int r0 = blockIdx.x * 32;
    const int c0 = blockIdx.y * 64;
    const int t = threadIdx.x;
    #pragma unroll
    for (int i = 0; i < 32; ++i) arow[i][t] = A[(size_t)(r0 + i) * Cn + t];
    __syncthreads();
    const int col = c0 + (t & 63);
    const int rg = (t >> 6) * 8;
    float acc[8];
    #pragma unroll
    for (int i = 0; i < 8; ++i) acc[i] = 0.f;
    const float* wr = W + (size_t)col * Cn;
    for (int k = 0; k < Cn; k += 4) {
        const float4 wv = *(const float4*)(wr + k);
        #pragma unroll
        for (int i = 0; i < 8; ++i)
            acc[i] += arow[rg + i][k] * wv.x + arow[rg + i][k+1] * wv.y
                    + arow[rg + i][k+2] * wv.z + arow[rg + i][k+3] * wv.w;
    }
    const float bv = bias ? bias[col] : 0.f;
    #pragma unroll
    for (int i = 0; i < 8; ++i) {
        float o = acc[i] + bv;
        if (res) o += res[(size_t)(r0 + rg + i) * Cn + col];
        if (BF16OUT) outb[(size_t)(r0 + rg + i) * Cn + col] = f2b(o);
        else         outf[(size_t)(r0 + rg + i) * Cn + col] = o;
    }
}

// ---- fused k'/v' projection (z picks matrix), bf16 out ----
__global__ __launch_bounds__(256) void linear_kv(
        const float* __restrict__ key, const float* __restrict__ Wk,
        const float* __restrict__ Wv, const float* __restrict__ bv,
        short* __restrict__ kpb, short* __restrict__ vpb) {
    __shared__ float arow[32][Cn];
    const int z = blockIdx.z;
    const float* W = z ? Wv : Wk;
    const float* bias = z ? bv : nullptr;
    short* outb = z ? vpb : kpb;
    const int r0 = blockIdx.x * 32;
    const int c0 = blockIdx.y * 64;
    const int t = threadIdx.x;
    #pragma unroll
    for (int i = 0; i < 32; ++i) arow[i][t] = key[(size_t)(r0 + i) * Cn + t];
    __syncthreads();
    const int col = c0 + (t & 63);
    const int rg = (t >> 6) * 8;
    float acc[8];
    #pragma unroll
    for (int i = 0; i < 8; ++i) acc[i] = 0.f;
    const float* wr = W + (size_t)col * Cn;
    for (int k = 0; k < Cn; k += 4) {
        const float4 wv = *(const float4*)(wr + k);
        #pragma unroll
        for (int i = 0; i < 8; ++i)
            acc[i] += arow[rg + i][k] * wv.x + arow[rg + i][k+1] * wv.y
                    + arow[rg + i][k+2] * wv.z + arow[rg + i][k+3] * wv.w;
    }
    const float bvv = bias ? bias[col] : 0.f;
    #pragma unroll
    for (int i = 0; i < 8; ++i)
        outb[(size_t)(r0 + rg + i) * Cn + col] = f2b(acc[i] + bvv);
}

// ---- fused attention: W1/W2 register-resident (256-VGPR budget), K/V async-LDS ----
// 512 threads = 8 waves; wave w owns output-channel slice [w*32, w*32+32) == head w.
__global__ __launch_bounds__(512, 1) void fused_attn(
        const float* __restrict__ qp, const short* __restrict__ kpb,
        const short* __restrict__ vpb, const float* __restrict__ qpos,
        const short* __restrict__ W1b, const short* __restrict__ W2b,
        const float* __restrict__ b1, const float* __restrict__ b2,
        const float* __restrict__ freqs, float* __restrict__ xout) {
    __shared__ __align__(16) char embS[MT * 512];   // 32 KB emb/S, XOR-swizzled
    __shared__ __align__(16) char kS[MT * 512];     // 32 KB K tile bf16 [m][c]
    __shared__ __align__(16) char vS[MT * 512];     // 32 KB V tile bf16 [m][c]
    __shared__ float tposS[Mn];                     // qpos row
    __shared__ float scb2[Hn * MT];                 // scores -> weights
    __shared__ float pacc[512];
    __shared__ float corrS[Hn], lS[Hn];
    // total LDS ~104.5 KB -> 1 block/CU -> 2 waves/SIMD -> 256-VGPR budget (no spill)

    const int t = threadIdx.x;
    const int lane = t & 63;
    const int w = t >> 6;                 // wave id = head id = col-slice id
    const int lr = lane & 15, lg = lane >> 4;

    // XCD-chunked bijective swizzle: 512 blocks = 8 XCDs x 64 contiguous
    const int qrow = ((blockIdx.x & 7) << 6) | (blockIdx.x >> 3);
    const int b = qrow >> 8;              // batch

    // --- W1/W2 register-resident B-fragments for cols c = w*32 + jb*16 + lr ---
    bf16x8 w1r[16], w2r[16];
    #pragma unroll
    for (int jb = 0; jb < 2; ++jb) {
        const short* p1 = W1b + (size_t)(w * 32 + jb * 16 + lr) * Cn + lg * 8;
        const short* p2 = W2b + (size_t)(w * 32 + jb * 16 + lr) * Cn + lg * 8;
        #pragma unroll
        for (int kk = 0; kk < 8; ++kk) {
            w1r[jb * 8 + kk] = *(const bf16x8*)(p1 + kk * 32);
            w2r[jb * 8 + kk] = *(const bf16x8*)(p2 + kk * 32);
        }
    }
    const int cA = w * 32 + lr, cB = cA + 16;
    const float b1v0 = b1[cA], b1v1 = b1[cB];
    const float b2v0 = b2[cA], b2v1 = b2[cB];
    const float q0 = qp[(size_t)qrow * Cn + cA];
    const float q1 = qp[(size_t)qrow * Cn + cB];
    const float fv = freqs[t & 127];
    tposS[t] = qpos[(size_t)qrow * Mn + t];
    float m_run = -1e30f, l_run = 0.f;
    float xacc = 0.f;                     // meaningful for t<256 (output channel t)
    const f32x4 vzero = {0.f, 0.f, 0.f, 0.f};
    __syncthreads();

    for (int m0 = 0; m0 < Mn; m0 += MT) {
        // issue async K/V tile loads (wave-uniform LDS dest, per-lane global src)
        {
            const size_t tbase = ((size_t)(b * Mn + m0)) * 512;
            #pragma unroll
            for (int i = 0; i < 4; ++i) {
                const int seg = (i * 8 + w) * 1024;
                async16((const char*)kpb + tbase + seg + lane * 16, kS + seg);
                async16((const char*)vpb + tbase + seg + lane * 16, vS + seg);
            }
        }

        // phase 1: embeddings -> embS (swizzled). thread: f = t&127, rows m = it*4 + (t>>7)
        {
            const int f = t & 127, mb = t >> 7;
            #pragma unroll 2
            for (int it = 0; it < 16; ++it) {
                const int m = it * 4 + mb;
                const float tv = tposS[m0 + m];
                float sv, cv;
                __sincosf(tv * fv, &sv, &cv);
                char* rowp = embS + m * 512;
                const int sw = (m & 7) << 4;
                *(short*)(rowp + ((f * 2) ^ sw)) = f2b(cv);         // cos -> [0:128)
                *(short*)(rowp + ((256 + f * 2) ^ sw)) = f2b(sv);   // sin -> [128:256)
            }
        }
        __syncthreads();                  // drains async loads (vmcnt) + emb writes

        // phase 2: GEMM1  hidden = emb @ W1^T
        f32x4 acc[4][2];
        #pragma unroll
        for (int pb = 0; pb < 4; ++pb) { acc[pb][0] = vzero; acc[pb][1] = vzero; }
        #pragma unroll
        for (int pb = 0; pb < 4; ++pb) {
            const int row = pb * 16 + lr;
            const int sw = (row & 7) << 4;
            const char* rowp = embS + row * 512;
            #pragma unroll
            for (int kk = 0; kk < 8; ++kk) {
                const bf16x8 a = *(const bf16x8*)(rowp + ((lg * 16 + kk * 64) ^ sw));
                acc[pb][0] = __builtin_amdgcn_mfma_f32_16x16x32_bf16(a, w1r[kk],     acc[pb][0], 0, 0, 0);
                acc[pb][1] = __builtin_amdgcn_mfma_f32_16x16x32_bf16(a, w1r[8 + kk], acc[pb][1], 0, 0, 0);
            }
        }
        __syncthreads();                   // all emb reads done

        // store S = silu(hidden + b1) back into embS (swizzled)
        #pragma unroll
        for (int pb = 0; pb < 4; ++pb) {
            #pragma unroll
            for (int jb = 0; jb < 2; ++jb) {
                const float bv = jb ? b1v1 : b1v0;
                const int j = w * 32 + jb * 16 + lr;
                #pragma unroll
                for (int r = 0; r < 4; ++r) {
                    const int row = pb * 16 + lg * 4 + r;   // C/D: row = 4*(lane>>4)+reg
                    float hv = acc[pb][jb][r] + bv;
                    hv = hv / (1.f + __expf(-hv));
                    *(short*)(embS + row * 512 + ((j * 2) ^ ((row & 7) << 4))) = f2b(hv);
                }
            }
        }
        __syncthreads();

        // phase 3: GEMM2  P = S @ W2^T  (P stays in registers)
        #pragma unroll
        for (int pb = 0; pb < 4; ++pb) { acc[pb][0] = vzero; acc[pb][1] = vzero; }
        #pragma unroll
        for (int pb = 0; pb < 4; ++pb) {
            const int row = pb * 16 + lr;
            const int sw = (row & 7) << 4;
            const char* rowp = embS + row * 512;
            #pragma unroll
            for (int kk = 0; kk < 8; ++kk) {
                const bf16x8 a = *(const bf16x8*)(rowp + ((lg * 16 + kk * 64) ^ sw));
                acc[pb][0] = __builtin_amdgcn_mfma_f32_16x16x32_bf16(a, w2r[kk],     acc[pb][0], 0, 0, 0);
                acc[pb][1] = __builtin_amdgcn_mfma_f32_16x16x32_bf16(a, w2r[8 + kk], acc[pb][1], 0, 0, 0);
            }
        }

        // phase 4: scores for head w from P-registers + kS
        #pragma unroll
        for (int pb = 0; pb < 4; ++pb) {
            #pragma unroll
            for (int r = 0; r < 4; ++r) {
                const int m = pb * 16 + lg * 4 + r;
                const float k0 = b2f(*(const short*)(kS + m * 512 + cA * 2));
                const float k1 = b2f(*(const short*)(kS + m * 512 + cB * 2));
                float v = (acc[pb][0][r] + b2v0) * q0 * k0
                        + (acc[pb][1][r] + b2v1) * q1 * k1;
                v += __shfl_xor(v, 1);
                v += __shfl_xor(v, 2);
                v += __shfl_xor(v, 4);
                v += __shfl_xor(v, 8);
                if (lr == 0) scb2[w * MT + m] = v * SCALE_;
            }
        }

        // phase 5: wave-local online softmax for head w (running m/l in registers)
        {
            const float s = scb2[w * MT + lane];
            float tmax = s;
            #pragma unroll
            for (int msk = 1; msk < 64; msk <<= 1) tmax = fmaxf(tmax, __shfl_xor(tmax, msk));
            const float mnew = fmaxf(m_run, tmax);
            const float corr = __expf(m_run - mnew);
            const float e = __expf(s - mnew);
            scb2[w * MT + lane] = e;
            float ss = e;
            #pragma unroll
            for (int msk = 1; msk < 64; msk <<= 1) ss += __shfl_xor(ss, msk);
            l_run = l_run * corr + ss;
            m_run = mnew;
            if (lane == 0) corrS[w] = corr;
        }
        __syncthreads();                   // weights + corrS visible to all

        // phase 6: PV partial sums. thread: c = t&255, m-half = t>>8
        {
            const int c = t & 255, half = t >> 8;
            const int h = c >> 5;
            const char* vb = vS + (half * 32) * 512 + c * 2;
            const float* wr2 = scb2 + h * MT + half * 32;
            float s = 0.f;
            #pragma unroll 8
            for (int m = 0; m < 32; ++m)
                s += wr2[m] * b2f(*(const short*)(vb + m * 512));
            pacc[t] = s;
        }
        __syncthreads();
        if (t < 256) xacc = xacc * corrS[t >> 5] + pacc[t] + pacc[t + 256];
        __syncthreads();                   // kS/vS/scb2/pacc free for next tile
    }

    if (lane == 0) lS[w] = l_run;
    __syncthreads();
    if (t < 256) xout[(size_t)qrow * Cn + t] = xacc / lS[t >> 5];
}

extern "C" void kernel_launch(void* const* d_in, const int* in_sizes, int n_in,
                              void* d_out, int out_size, void* d_ws, size_t ws_size,
                              hipStream_t stream) {
    const float* query = (const float*)d_in[0];
    const float* key   = (const float*)d_in[1];
    const float* qpos  = (const float*)d_in[2];
    const float* Wq    = (const float*)d_in[3];
    const float* bq    = (const float*)d_in[4];
    const float* Wk    = (const float*)d_in[5];
    const float* Wv    = (const float*)d_in[6];
    const float* bv    = (const float*)d_in[7];
    const float* Wo    = (const float*)d_in[8];
    const float* bo    = (const float*)d_in[9];
    const float* W1    = (const float*)d_in[10];
    const float* b1    = (const float*)d_in[11];
    const float* W2    = (const float*)d_in[12];
    const float* b2    = (const float*)d_in[13];
    const float* freqs = (const float*)d_in[14];
    float* out = (float*)d_out;

    char* ws = (char*)d_ws;
    float* qp  = (float*)(ws);                 // 512 KB  (B*N*C f32)
    short* kpb = (short*)(ws + 524288);        // 512 KB  (B*M*C bf16)
    short* vpb = (short*)(ws + 1048576);       // 512 KB
    float* xo  = (float*)(ws + 1572864);       // 512 KB
    short* W1b = (short*)(ws + 2097152);       // 128 KB bf16
    short* W2b = (short*)(ws + 2228224);       // 128 KB bf16

    convert_w<<<256, 256, 0, stream>>>(W1, W2, W1b, W2b);
    linear_rc<false><<<dim3(16, 4), 256, 0, stream>>>(query, Wq, bq, nullptr, qp, nullptr);
    linear_kv<<<dim3(32, 4, 2), 256, 0, stream>>>(key, Wk, Wv, bv, kpb, vpb);
    fused_attn<<<Bn * Nn, 512, 0, stream>>>(qp, kpb, vpb, qpos, W1b, W2b, b1, b2, freqs, xo);
    linear_rc<false><<<dim3(16, 4), 256, 0, stream>>>(xo, Wo, bo, query, out, nullptr);
}

// Round 6
// 299.818 us; speedup vs baseline: 3.2654x; 1.0552x over previous
//
#include <hip/hip_runtime.h>

// Problem constants (fixed by the reference)
#define Bn 2
#define Nn 256
#define Mn 512
#define Cn 256
#define Hn 8
#define MT 64             // m-tile size in fused kernel
#define SCALE_ 0.17677669529663687f   // Dh^-0.5, Dh=32

typedef short bf16x8 __attribute__((ext_vector_type(8)));
typedef short bf16x4 __attribute__((ext_vector_type(4)));
typedef float f32x4 __attribute__((ext_vector_type(4)));

static __device__ __forceinline__ float b2f(short s) {
    unsigned u = ((unsigned)(unsigned short)s) << 16;
    return __builtin_bit_cast(float, u);
}
static __device__ __forceinline__ short f2b(float f) {   // RNE f32->bf16
    unsigned u = __builtin_bit_cast(unsigned, f);
    u += 0x7fffu + ((u >> 16) & 1u);
    return (short)(u >> 16);
}
static __device__ __forceinline__ void async16(const void* g, void* l) {
    __builtin_amdgcn_global_load_lds(
        (const __attribute__((address_space(1))) unsigned int*)g,
        (__attribute__((address_space(3))) unsigned int*)l, 16, 0, 0);
}
// kT/vT LDS layout: row c base = (c>>3)*1040 + (c&7)*128 (16B pad per 8 rows),
// chunk ch=mm>>3 stored at position ch^(c&7). Conflict-spread for both
// row-parallel (phase 4) and col-parallel (phase 6) access.
static __device__ __forceinline__ int taddr(int c, int mm) {
    return (c >> 3) * 1040 + (c & 7) * 128 + (((mm >> 3) ^ (c & 7)) << 4) + (mm & 7) * 2;
}

// ---- prep: W1/W2 convert + q/k/v projections (k/v written TRANSPOSED bf16) ----
__global__ __launch_bounds__(256) void prep(
        const float* __restrict__ query, const float* __restrict__ key,
        const float* __restrict__ Wq, const float* __restrict__ bq,
        const float* __restrict__ Wk, const float* __restrict__ Wv,
        const float* __restrict__ bv, const float* __restrict__ W1,
        const float* __restrict__ W2, short* __restrict__ W1b,
        short* __restrict__ W2b, float* __restrict__ qp,
        short* __restrict__ kTb, short* __restrict__ vTb) {
    __shared__ float arow[32][Cn];
    const int bid = blockIdx.x;
    const int t = threadIdx.x;
    if (bid < 256) {                       // task: convert W1/W2 to bf16
        const int i = bid * 256 + t;
        W1b[i] = f2b(W1[i]);
        W2b[i] = f2b(W2[i]);
        return;
    }
    int task, id;
    if (bid < 320)      { task = 0; id = bid - 256; }   // q': 64 blocks
    else if (bid < 448) { task = 1; id = bid - 320; }   // k': 128 blocks
    else                { task = 2; id = bid - 448; }   // v': 128 blocks
    const int r0 = (id >> 2) * 32;
    const int c0 = (id & 3) * 64;
    const float* A = (task == 0) ? query : key;
    const float* W = (task == 0) ? Wq : (task == 1 ? Wk : Wv);
    #pragma unroll
    for (int i = 0; i < 32; ++i) arow[i][t] = A[(size_t)(r0 + i) * Cn + t];
    __syncthreads();
    const int col = c0 + (t & 63);
    const int rg = (t >> 6) * 8;
    float acc[8];
    #pragma unroll
    for (int i = 0; i < 8; ++i) acc[i] = 0.f;
    const float* wr = W + (size_t)col * Cn;
    for (int k = 0; k < Cn; k += 4) {
        const float4 wv = *(const float4*)(wr + k);
        #pragma unroll
        for (int i = 0; i < 8; ++i)
            acc[i] += arow[rg + i][k] * wv.x + arow[rg + i][k+1] * wv.y
                    + arow[rg + i][k+2] * wv.z + arow[rg + i][k+3] * wv.w;
    }
    if (task == 0) {
        const float bvv = bq[col];
        #pragma unroll
        for (int i = 0; i < 8; ++i)
            qp[(size_t)(r0 + rg + i) * Cn + col] = acc[i] + bvv;
    } else {
        const float bvv = (task == 2) ? bv[col] : 0.f;
        short* outb = (task == 2) ? vTb : kTb;
        const int b = r0 >> 9, mloc = (r0 & 511) + rg;
        bf16x8 p;
        #pragma unroll
        for (int i = 0; i < 8; ++i) p[i] = f2b(acc[i] + bvv);
        *(bf16x8*)(outb + ((size_t)(b * Cn + col)) * Mn + mloc) = p;
    }
}

// ---- fused attention: W1/W2 pinned register-resident, K/V transposed LDS ----
// 512 threads = 8 waves; wave w owns output-channel slice [w*32, w*32+32) == head w.
__global__ __launch_bounds__(512)
__attribute__((amdgpu_waves_per_eu(2, 2)))
void fused_attn(
        const float* __restrict__ qp, const short* __restrict__ kTb,
        const short* __restrict__ vTb, const float* __restrict__ qpos,
        const short* __restrict__ W1b, const short* __restrict__ W2b,
        const float* __restrict__ b1, const float* __restrict__ b2,
        const float* __restrict__ freqs, float* __restrict__ xout) {
    __shared__ __align__(16) char embS[MT * 512];   // 32 KB emb/S, XOR-swizzled
    __shared__ __align__(16) char kTs[32 * 1040];   // 32.5 KB K tile bf16 [c][m] padded+XOR
    __shared__ __align__(16) char vTs[32 * 1040];   // 32.5 KB V tile
    __shared__ float tposS[Mn];
    __shared__ float scb2[Hn * MT];                 // scores -> weights
    __shared__ float pacc[512];
    __shared__ float corrS[Hn], lS[Hn];
    // ~105.5 KB -> 1 block/CU -> 2 waves/SIMD -> 256-VGPR budget

    const int t = threadIdx.x;
    const int lane = t & 63;
    const int w = t >> 6;                 // wave id = head id = col-slice id
    const int lr = lane & 15, lg = lane >> 4;

    // XCD-chunked bijective swizzle: 512 blocks = 8 XCDs x 64 contiguous
    const int qrow = ((blockIdx.x & 7) << 6) | (blockIdx.x >> 3);
    const int b = qrow >> 8;              // batch

    // --- W1/W2 register-resident B-fragments for cols c = w*32 + jb*16 + lr ---
    bf16x8 w1r[16], w2r[16];
    #pragma unroll
    for (int jb = 0; jb < 2; ++jb) {
        const short* p1 = W1b + (size_t)(w * 32 + jb * 16 + lr) * Cn + lg * 8;
        const short* p2 = W2b + (size_t)(w * 32 + jb * 16 + lr) * Cn + lg * 8;
        #pragma unroll
        for (int kk = 0; kk < 8; ++kk) {
            w1r[jb * 8 + kk] = *(const bf16x8*)(p1 + kk * 32);
            w2r[jb * 8 + kk] = *(const bf16x8*)(p2 + kk * 32);
        }
    }
    // Pin: opaque defs cannot be rematerialized -> stay register-resident.
    #pragma unroll
    for (int i = 0; i < 16; ++i) {
        asm volatile("" : "+v"(w1r[i]));
        asm volatile("" : "+v"(w2r[i]));
    }

    const int cA = w * 32 + lr, cB = cA + 16;
    const float b1v0 = b1[cA], b1v1 = b1[cB];
    const float b2v0 = b2[cA], b2v1 = b2[cB];
    const float q0 = qp[(size_t)qrow * Cn + cA];
    const float q1 = qp[(size_t)qrow * Cn + cB];
    // per-thread frequency slice (emb phase: thread = one m x 16 f's)
    const int fg = t & 7;
    float fr[16];
    #pragma unroll
    for (int j = 0; j < 16; ++j) fr[j] = freqs[fg * 16 + j];
    tposS[t] = qpos[(size_t)qrow * Mn + t];
    float m_run = -1e30f, l_run = 0.f;
    float xacc = 0.f;                     // meaningful for t<256 (output channel t)
    const f32x4 vzero = {0.f, 0.f, 0.f, 0.f};
    // staging lane constants: seg s, lane l -> row c=s*8+(l>>3), chunk ch=(l&7)^(l>>3)
    const int st_c = lane >> 3;
    const int st_ch = (lane & 7) ^ st_c;
    __syncthreads();

    for (int m0 = 0; m0 < Mn; m0 += MT) {
        // issue async K/V tile loads (linear LDS dest, source-side XOR swizzle)
        {
            const size_t gb = (size_t)b * Cn * Mn + m0 + st_ch * 8;
            #pragma unroll
            for (int i = 0; i < 4; ++i) {
                const int seg = i * 8 + w;
                const size_t srow = gb + (size_t)(seg * 8 + st_c) * Mn;
                async16(kTb + srow, kTs + seg * 1040);
                async16(vTb + srow, vTs + seg * 1040);
            }
        }

        // phase 1: embeddings -> embS (swizzled b128 writes). thread: m = t>>3, f = fg*16..+15
        {
            const int m = t >> 3;
            const float tv = tposS[m0 + m];
            bf16x8 pc[2], ps[2];
            #pragma unroll
            for (int j = 0; j < 16; ++j) {
                float sv, cv;
                __sincosf(tv * fr[j], &sv, &cv);
                pc[j >> 3][j & 7] = f2b(cv);
                ps[j >> 3][j & 7] = f2b(sv);
            }
            char* rowp = embS + m * 512;
            const int sw = (m & 7) << 4;
            *(bf16x8*)(rowp + ((fg * 32) ^ sw)) = pc[0];
            *(bf16x8*)(rowp + ((fg * 32 + 16) ^ sw)) = pc[1];
            *(bf16x8*)(rowp + ((256 + fg * 32) ^ sw)) = ps[0];
            *(bf16x8*)(rowp + ((256 + fg * 32 + 16) ^ sw)) = ps[1];
        }
        __syncthreads();                  // drains async vmcnt + emb visible

        // phase 2: GEMM1  hidden = emb @ W1^T
        f32x4 acc[4][2];
        #pragma unroll
        for (int pb = 0; pb < 4; ++pb) { acc[pb][0] = vzero; acc[pb][1] = vzero; }
        #pragma unroll
        for (int pb = 0; pb < 4; ++pb) {
            const int row = pb * 16 + lr;
            const int sw = (row & 7) << 4;
            const char* rowp = embS + row * 512;
            #pragma unroll
            for (int kk = 0; kk < 8; ++kk) {
                const bf16x8 a = *(const bf16x8*)(rowp + ((lg * 16 + kk * 64) ^ sw));
                acc[pb][0] = __builtin_amdgcn_mfma_f32_16x16x32_bf16(a, w1r[kk],     acc[pb][0], 0, 0, 0);
                acc[pb][1] = __builtin_amdgcn_mfma_f32_16x16x32_bf16(a, w1r[8 + kk], acc[pb][1], 0, 0, 0);
            }
        }
        __syncthreads();                   // all emb reads done

        // store S = silu(hidden + b1) back into embS (swizzled)
        #pragma unroll
        for (int pb = 0; pb < 4; ++pb) {
            #pragma unroll
            for (int jb = 0; jb < 2; ++jb) {
                const float bv = jb ? b1v1 : b1v0;
                const int j = w * 32 + jb * 16 + lr;
                #pragma unroll
                for (int r = 0; r < 4; ++r) {
                    const int row = pb * 16 + lg * 4 + r;   // C/D: row = 4*(lane>>4)+reg
                    float hv = acc[pb][jb][r] + bv;
                    hv = hv / (1.f + __expf(-hv));
                    *(short*)(embS + row * 512 + ((j * 2) ^ ((row & 7) << 4))) = f2b(hv);
                }
            }
        }
        __syncthreads();

        // phase 3: GEMM2  P = S @ W2^T  (P stays in registers)
        #pragma unroll
        for (int pb = 0; pb < 4; ++pb) { acc[pb][0] = vzero; acc[pb][1] = vzero; }
        #pragma unroll
        for (int pb = 0; pb < 4; ++pb) {
            const int row = pb * 16 + lr;
            const int sw = (row & 7) << 4;
            const char* rowp = embS + row * 512;
            #pragma unroll
            for (int kk = 0; kk < 8; ++kk) {
                const bf16x8 a = *(const bf16x8*)(rowp + ((lg * 16 + kk * 64) ^ sw));
                acc[pb][0] = __builtin_amdgcn_mfma_f32_16x16x32_bf16(a, w2r[kk],     acc[pb][0], 0, 0, 0);
                acc[pb][1] = __builtin_amdgcn_mfma_f32_16x16x32_bf16(a, w2r[8 + kk], acc[pb][1], 0, 0, 0);
            }
        }

        // phase 4: scores for head w from P-registers + kTs (b64 vector reads)
        #pragma unroll
        for (int pb = 0; pb < 4; ++pb) {
            const int mmb = pb * 16 + lg * 4;
            const bf16x4 k4a = *(const bf16x4*)(kTs + taddr(cA, mmb));
            const bf16x4 k4b = *(const bf16x4*)(kTs + taddr(cB, mmb));
            #pragma unroll
            for (int r = 0; r < 4; ++r) {
                float v = (acc[pb][0][r] + b2v0) * q0 * b2f(k4a[r])
                        + (acc[pb][1][r] + b2v1) * q1 * b2f(k4b[r]);
                v += __shfl_xor(v, 1);
                v += __shfl_xor(v, 2);
                v += __shfl_xor(v, 4);
                v += __shfl_xor(v, 8);
                if (lr == 0) scb2[w * MT + mmb + r] = v * SCALE_;
            }
        }

        // phase 5: wave-local online softmax for head w (running m/l in registers)
        {
            const float s = scb2[w * MT + lane];
            float tmax = s;
            #pragma unroll
            for (int msk = 1; msk < 64; msk <<= 1) tmax = fmaxf(tmax, __shfl_xor(tmax, msk));
            const float mnew = fmaxf(m_run, tmax);
            const float corr = __expf(m_run - mnew);
            const float e = __expf(s - mnew);
            scb2[w * MT + lane] = e;
            float ss = e;
            #pragma unroll
            for (int msk = 1; msk < 64; msk <<= 1) ss += __shfl_xor(ss, msk);
            l_run = l_run * corr + ss;
            m_run = mnew;
            if (lane == 0) corrS[w] = corr;
        }
        __syncthreads();                   // weights + corrS visible to all

        // phase 6: PV partial sums. thread: c = t&255, m-half = t>>8 (b128 V reads)
        {
            const int c = t & 255, half = t >> 8;
            const int h = c >> 5;
            const int rowb = (c >> 3) * 1040 + (c & 7) * 128;
            const int c7 = c & 7;
            const float* wr2 = scb2 + h * MT + half * 32;
            float s = 0.f;
            #pragma unroll
            for (int i = 0; i < 4; ++i) {
                const bf16x8 v8 = *(const bf16x8*)(vTs + rowb + (((half * 4 + i) ^ c7) << 4));
                const float4 wa = *(const float4*)(wr2 + i * 8);
                const float4 wb = *(const float4*)(wr2 + i * 8 + 4);
                s += wa.x * b2f(v8[0]) + wa.y * b2f(v8[1]) + wa.z * b2f(v8[2]) + wa.w * b2f(v8[3])
                   + wb.x * b2f(v8[4]) + wb.y * b2f(v8[5]) + wb.z * b2f(v8[6]) + wb.w * b2f(v8[7]);
            }
            pacc[t] = s;
        }
        __syncthreads();
        if (t < 256) xacc = xacc * corrS[t >> 5] + pacc[t] + pacc[t + 256];
        // no trailing barrier: next-tile writes (kTs/vTs/embS/scb2) are all
        // separated from this tile's readers by the barriers above.
    }

    if (lane == 0) lS[w] = l_run;
    __syncthreads();
    if (t < 256) xout[(size_t)qrow * Cn + t] = xacc / lS[t >> 5];
}

// ---- out-projection: out = x @ Wo^T + bo + query ----
__global__ __launch_bounds__(256) void linear_out(
        const float* __restrict__ A, const float* __restrict__ W,
        const float* __restrict__ bias, const float* __restrict__ res,
        float* __restrict__ out) {
    __shared__ float arow[32][Cn];
    const int r0 = blockIdx.x * 32;
    const int c0 = blockIdx.y * 64;
    const int t = threadIdx.x;
    #pragma unroll
    for (int i = 0; i < 32; ++i) arow[i][t] = A[(size_t)(r0 + i) * Cn + t];
    __syncthreads();
    const int col = c0 + (t & 63);
    const int rg = (t >> 6) * 8;
    float acc[8];
    #pragma unroll
    for (int i = 0; i < 8; ++i) acc[i] = 0.f;
    const float* wr = W + (size_t)col * Cn;
    for (int k = 0; k < Cn; k += 4) {
        const float4 wv = *(const float4*)(wr + k);
        #pragma unroll
        for (int i = 0; i < 8; ++i)
            acc[i] += arow[rg + i][k] * wv.x + arow[rg + i][k+1] * wv.y
                    + arow[rg + i][k+2] * wv.z + arow[rg + i][k+3] * wv.w;
    }
    const float bvv = bias[col];
    #pragma unroll
    for (int i = 0; i < 8; ++i)
        out[(size_t)(r0 + rg + i) * Cn + col] =
            acc[i] + bvv + res[(size_t)(r0 + rg + i) * Cn + col];
}

extern "C" void kernel_launch(void* const* d_in, const int* in_sizes, int n_in,
                              void* d_out, int out_size, void* d_ws, size_t ws_size,
                              hipStream_t stream) {
    const float* query = (const float*)d_in[0];
    const float* key   = (const float*)d_in[1];
    const float* qpos  = (const float*)d_in[2];
    const float* Wq    = (const float*)d_in[3];
    const float* bq    = (const float*)d_in[4];
    const float* Wk    = (const float*)d_in[5];
    const float* Wv    = (const float*)d_in[6];
    const float* bv    = (const float*)d_in[7];
    const float* Wo    = (const float*)d_in[8];
    const float* bo    = (const float*)d_in[9];
    const float* W1    = (const float*)d_in[10];
    const float* b1    = (const float*)d_in[11];
    const float* W2    = (const float*)d_in[12];
    const float* b2    = (const float*)d_in[13];
    const float* freqs = (const float*)d_in[14];
    float* out = (float*)d_out;

    char* ws = (char*)d_ws;
    float* qp  = (float*)(ws);                 // 512 KB  (B*N*C f32)
    short* kTb = (short*)(ws + 524288);        // 512 KB  (B*C*M bf16, transposed)
    short* vTb = (short*)(ws + 1048576);       // 512 KB
    float* xo  = (float*)(ws + 1572864);       // 512 KB
    short* W1b = (short*)(ws + 2097152);       // 128 KB bf16
    short* W2b = (short*)(ws + 2228224);       // 128 KB bf16

    prep<<<576, 256, 0, stream>>>(query, key, Wq, bq, Wk, Wv, bv, W1, W2,
                                  W1b, W2b, qp, kTb, vTb);
    fused_attn<<<Bn * Nn, 512, 0, stream>>>(qp, kTb, vTb, qpos, W1b, W2b, b1, b2, freqs, xo);
    linear_out<<<dim3(16, 4), 256, 0, stream>>>(xo, Wo, bo, query, out);
}